// Round 5
// baseline (7043.728 us; speedup 1.0000x reference)
//
#include <hip/hip_runtime.h>
#include <hip/hip_bf16.h>
#include <math.h>

#define B_SZ 8
#define NT 2048
#define M_TOT (B_SZ * NT)      // 16384
#define DM 1024                // d_model
#define ZD 32
#define IN0 2080               // 2*DM + ZD
#define HID 2048
#define OUT1 1024
#define NCH 13                 // feature chunks: silu + T1..T12 (T0 folded into bias)
#define K0 (NCH * IN0)         // 27040
#define K1 (NCH * HID)         // 26624
#define RMS_EPS 1e-6f

typedef __bf16 bf16;
typedef __bf16 bf16x8 __attribute__((ext_vector_type(8)));
typedef float f32x4 __attribute__((ext_vector_type(4)));

// ---------------------------------------------------------------- utilities
__device__ __forceinline__ void gload16(const void* g, void* l) {
    __builtin_amdgcn_global_load_lds(
        (const __attribute__((address_space(1))) void*)g,
        (__attribute__((address_space(3))) void*)l, 16, 0, 0);
}

__device__ __forceinline__ float rb(float x) { return (float)(bf16)x; }  // round-to-bf16

// ---------------------------------------------------- weight convert (f32->bf16, transpose to [N][K])
// chunk c: c==0 -> base[IN][OUT], else poly[c][IN][OUT]
// dst: bf16 [OUT][NCH*IN], dst[n][c*IN + i] = bf16(src_c[i][n])
__global__ __launch_bounds__(256) void convert_w(const float* __restrict__ base,
                                                 const float* __restrict__ poly,
                                                 bf16* __restrict__ dst, int IN, int OUT) {
    __shared__ float tile[32][33];
    int c = blockIdx.z;
    const float* src = (c == 0) ? base : (poly + (size_t)c * IN * OUT);
    int i0 = blockIdx.x * 32, n0 = blockIdx.y * 32;
    int tx = threadIdx.x, ty = threadIdx.y;  // (32,8)
#pragma unroll
    for (int r = 0; r < 4; r++)
        tile[ty + r * 8][tx] = src[(size_t)(i0 + ty + r * 8) * OUT + n0 + tx];
    __syncthreads();
    size_t ldd = (size_t)NCH * IN;
#pragma unroll
    for (int r = 0; r < 4; r++) {
        int n = n0 + ty + r * 8;
        int i = i0 + tx;
        dst[(size_t)n * ldd + (size_t)c * IN + i] = (bf16)tile[tx][ty + r * 8];
    }
}

// bias[n] = f32-sum_i bf16(poly0[i][n])  (the ones @ pw[0] matmul: bf16 inputs, f32 accum)
__global__ __launch_bounds__(256) void col_sum_bf16(const float* __restrict__ w,
                                                    float* __restrict__ bias, int IN, int OUT) {
    int n = blockIdx.x * 256 + threadIdx.x;
    if (n >= OUT) return;
    float s = 0.f;
#pragma unroll 8
    for (int i = 0; i < IN; i++) s += (float)(bf16)w[(size_t)i * OUT + n];
    bias[n] = s;
}

// ------------------------------------------------------------ feature build
// silu emulated with PER-OP bf16 rounding (jax.nn.silu on a bf16 array):
//   e = bf16(exp(-x)); d = bf16(1+e); s = bf16(1/d); silu = bf16(x*s)
__device__ __forceinline__ void write_features(bf16* row, float v, int stride) {
    float xb = rb(v);
    float e  = rb(expf(-xb));
    float d  = rb(1.f + e);
    float sg = rb(1.f / d);
    row[0] = (bf16)(xb * sg);
    float xs = tanhf(v);                              // tanh of f32 x (stays f32)
    row[stride] = (bf16)xs;                           // T1
    float Tp = 1.f, Tc = xs;
#pragma unroll
    for (int k = 2; k < NCH; k++) {
        float Tn = 2.f * xs * Tc - Tp;                // recursion in f32
        row[(size_t)k * stride] = (bf16)Tn;
        Tp = Tc; Tc = Tn;
    }
}

__global__ __launch_bounds__(256) void build_f0(const float* __restrict__ h_x,
                                                const int* __restrict__ tp,
                                                const float* __restrict__ z,
                                                const float* __restrict__ pe,
                                                bf16* __restrict__ F, int m0, int rows) {
    int id = blockIdx.x * 256 + threadIdx.x;
    if (id >= rows * IN0) return;
    int ml = id / IN0;
    int i = id - ml * IN0;
    int mg = m0 + ml;
    int b = mg >> 11;        // / NT
    float v;
    if (i < DM) v = h_x[((size_t)b * 128 + 127) * DM + i];
    else if (i < 2 * DM) v = pe[(size_t)tp[mg] * DM + (i - DM)];
    else v = z[(size_t)mg * ZD + (i - 2 * DM)];
    write_features(F + (size_t)ml * K0 + i, v, IN0);
}

__global__ __launch_bounds__(256) void build_f1(const float* __restrict__ Hn,
                                                bf16* __restrict__ F, int rows) {
    int id = blockIdx.x * 256 + threadIdx.x;
    if (id >= rows * HID) return;
    int ml = id >> 11;
    int i = id & 2047;
    write_features(F + (size_t)ml * K1 + i, Hn[id], HID);
}

// ------------------------------------------------------------------ RMSNorm (in place, f32)
template <int N>
__global__ __launch_bounds__(256) void rmsnorm_k(float* __restrict__ H,
                                                 const float* __restrict__ scale) {
    constexpr int VPT = N / (4 * 256);
    int row = blockIdx.x;
    float4* p = (float4*)(H + (size_t)row * N);
    const float4* sc = (const float4*)scale;
    float4 v[VPT];
    float s = 0.f;
#pragma unroll
    for (int j = 0; j < VPT; j++) {
        v[j] = p[threadIdx.x + j * 256];
        s += v[j].x * v[j].x + v[j].y * v[j].y + v[j].z * v[j].z + v[j].w * v[j].w;
    }
#pragma unroll
    for (int o = 32; o > 0; o >>= 1) s += __shfl_down(s, o, 64);
    __shared__ float wsum[4];
    if ((threadIdx.x & 63) == 0) wsum[threadIdx.x >> 6] = s;
    __syncthreads();
    s = wsum[0] + wsum[1] + wsum[2] + wsum[3];
    float rs = rsqrtf(s * (1.0f / N) + RMS_EPS);
#pragma unroll
    for (int j = 0; j < VPT; j++) {
        float4 sv = sc[threadIdx.x + j * 256];
        float4 o_;
        o_.x = v[j].x * rs * sv.x;
        o_.y = v[j].y * rs * sv.y;
        o_.z = v[j].z * rs * sv.z;
        o_.w = v[j].w * rs * sv.w;
        p[threadIdx.x + j * 256] = o_;
    }
}

// ------------------------------------------------------------------ GEMM with bf16 stepwise accumulation
// out = bf16(chunk0); out = bf16(out + bf16(bias)); out = bf16(out + bf16(chunk_c)) c=1..12
#define BM 128
#define BN 128
#define BK 32
#define GROUP_M 8

__global__ __launch_bounds__(256, 2) void gemm_bias(const bf16* __restrict__ A,
                                                    const bf16* __restrict__ Bt,
                                                    const float* __restrict__ bias,
                                                    float* __restrict__ C,
                                                    int Mrows, int N, int IN) {
    __shared__ __align__(16) bf16 As[BM * BK];   // [m][k]
    __shared__ __align__(16) bf16 Bs[BN * BK];   // [n][k]

    const int K = NCH * IN;
    int nbm = Mrows / BM, nbn = N / BN;
    int pid = blockIdx.x;
    int width = GROUP_M * nbn;
    int group_id = pid / width;
    int first_m = group_id * GROUP_M;
    int gsz = min(nbm - first_m, GROUP_M);
    int mb = first_m + (pid % width) % gsz;
    int nb = (pid % width) / gsz;

    int tid = threadIdx.x;
    int lane = tid & 63, wid = tid >> 6;
    int wm = wid >> 1, wn = wid & 1;  // 2x2 wave grid, each wave 64x64

    const bf16* Ab = A + (size_t)mb * BM * K;
    const bf16* Bb = Bt + (size_t)nb * BN * K;

    const int q0 = tid, q1 = tid + 256;
    const int r0 = q0 >> 2, kk0 = (q0 & 3) * 8;
    const int r1 = q1 >> 2, kk1 = (q1 & 3) * 8;

    const int arow = wm * 64 + (lane & 15);
    const int brow = wn * 64 + (lane & 15);
    const int kqo = (lane >> 4) * 8;

    const int lcol = lane & 15, lrow4 = (lane >> 4) * 4;
    const int crow0 = mb * BM + wm * 64;
    const int ccol0 = nb * BN + wn * 64;

    f32x4 outv[4][4] = {};

    for (int c = 0; c < NCH; c++) {
        f32x4 acc[4][4] = {};
        const size_t cb = (size_t)c * IN;
        for (int ks = 0; ks < IN; ks += BK) {
            const size_t kb = cb + ks;
            gload16(Ab + (size_t)r0 * K + kb + kk0, (char*)As + q0 * 16);
            gload16(Ab + (size_t)r1 * K + kb + kk1, (char*)As + q1 * 16);
            gload16(Bb + (size_t)r0 * K + kb + kk0, (char*)Bs + q0 * 16);
            gload16(Bb + (size_t)r1 * K + kb + kk1, (char*)Bs + q1 * 16);
            __syncthreads();

            bf16x8 af[4], bfr[4];
#pragma unroll
            for (int am = 0; am < 4; am++)
                af[am] = *(const bf16x8*)&As[(arow + am * 16) * BK + kqo];
#pragma unroll
            for (int bn = 0; bn < 4; bn++)
                bfr[bn] = *(const bf16x8*)&Bs[(brow + bn * 16) * BK + kqo];
#pragma unroll
            for (int am = 0; am < 4; am++)
#pragma unroll
                for (int bn = 0; bn < 4; bn++)
                    acc[am][bn] = __builtin_amdgcn_mfma_f32_16x16x32_bf16(af[am], bfr[bn], acc[am][bn], 0, 0, 0);
            __syncthreads();
        }
        // fold chunk into running bf16 sum: out = bf16(out + bf16(chunk))
#pragma unroll
        for (int am = 0; am < 4; am++)
#pragma unroll
            for (int bn = 0; bn < 4; bn++)
#pragma unroll
                for (int e = 0; e < 4; e++)
                    outv[am][bn][e] = rb(outv[am][bn][e] + rb(acc[am][bn][e]));
        if (c == 0) {
            // T0 chunk (ones @ pw[0]), added second in reference order
#pragma unroll
            for (int bn = 0; bn < 4; bn++) {
                float bv = rb(bias[ccol0 + bn * 16 + lcol]);
#pragma unroll
                for (int am = 0; am < 4; am++)
#pragma unroll
                    for (int e = 0; e < 4; e++)
                        outv[am][bn][e] = rb(outv[am][bn][e] + bv);
            }
        }
    }

    // epilogue: C/D layout col=lane&15, row=(lane>>4)*4+reg
#pragma unroll
    for (int bn = 0; bn < 4; bn++) {
        int col = ccol0 + bn * 16 + lcol;
#pragma unroll
        for (int am = 0; am < 4; am++) {
            int row = crow0 + am * 16 + lrow4;
#pragma unroll
            for (int e = 0; e < 4; e++)
                C[(size_t)(row + e) * N + col] = outv[am][bn][e];
        }
    }
}

// ------------------------------------------------------------------ host
extern "C" void kernel_launch(void* const* d_in, const int* in_sizes, int n_in,
                              void* d_out, int out_size, void* d_ws, size_t ws_size,
                              hipStream_t stream) {
    const float* h_x   = (const float*)d_in[0];
    const int*   tp    = (const int*)d_in[1];
    const float* z     = (const float*)d_in[2];
    const float* pe    = (const float*)d_in[3];
    const float* base0 = (const float*)d_in[4];
    const float* poly0 = (const float*)d_in[5];
    const float* rms0  = (const float*)d_in[6];
    const float* base1 = (const float*)d_in[7];
    const float* poly1 = (const float*)d_in[8];
    const float* rms1  = (const float*)d_in[9];
    float* out = (float*)d_out;

    char* ws = (char*)d_ws;
    size_t off = 0;
    bf16* wb0 = (bf16*)(ws + off); off += (size_t)HID * K0 * 2;    // 110,755,840
    bf16* wb1 = (bf16*)(ws + off); off += (size_t)OUT1 * K1 * 2;   //  54,525,952
    float* bias0 = (float*)(ws + off); off += HID * 4;
    float* bias1 = (float*)(ws + off); off += OUT1 * 4;
    size_t fixed = off;

    // row-chunk to fit workspace: per row need F (K0 bf16) + H0 (HID f32)
    size_t per_row = (size_t)K0 * 2 + (size_t)HID * 4;
    size_t avail = ws_size > fixed ? ws_size - fixed : 0;
    long long chunk_ll = (long long)(avail / per_row);
    int chunk = (int)(chunk_ll > M_TOT ? M_TOT : chunk_ll);
    chunk &= ~127;                 // multiple of 128
    if (chunk < 128) chunk = 128;  // last resort

    bf16* F = (bf16*)(ws + off); off += (size_t)chunk * K0 * 2;
    float* H0 = (float*)(ws + off);

    dim3 tb(32, 8);
    convert_w<<<dim3(IN0 / 32, HID / 32, NCH), tb, 0, stream>>>(base0, poly0, wb0, IN0, HID);
    convert_w<<<dim3(HID / 32, OUT1 / 32, NCH), tb, 0, stream>>>(base1, poly1, wb1, HID, OUT1);
    col_sum_bf16<<<HID / 256, 256, 0, stream>>>(poly0, bias0, IN0, HID);
    col_sum_bf16<<<OUT1 / 256, 256, 0, stream>>>(poly1, bias1, HID, OUT1);

    for (int m0 = 0; m0 < M_TOT; m0 += chunk) {
        int rows = (M_TOT - m0 < chunk) ? (M_TOT - m0) : chunk;
        build_f0<<<(rows * IN0 + 255) / 256, 256, 0, stream>>>(h_x, tp, z, pe, F, m0, rows);
        gemm_bias<<<(rows / BM) * (HID / BN), 256, 0, stream>>>(F, wb0, bias0, H0, rows, HID, IN0);
        rmsnorm_k<HID><<<rows, 256, 0, stream>>>(H0, rms0);
        build_f1<<<(rows * HID) / 256, 256, 0, stream>>>(H0, F, rows);
        float* o = out + (size_t)m0 * OUT1;
        gemm_bias<<<(rows / BM) * (OUT1 / BN), 256, 0, stream>>>(F, wb1, bias1, o, rows, OUT1, HID);
        rmsnorm_k<OUT1><<<rows, 256, 0, stream>>>(o, rms1);
    }
}

// Round 6
// 5139.745 us; speedup vs baseline: 1.3704x; 1.3704x over previous
//
#include <hip/hip_runtime.h>
#include <hip/hip_bf16.h>
#include <math.h>

#define B_SZ 8
#define NT 2048
#define M_TOT (B_SZ * NT)      // 16384
#define DM 1024                // d_model
#define ZD 32
#define IN0 2080               // 2*DM + ZD
#define HID 2048
#define OUT1 1024
#define NCH 13                 // feature chunks: silu + T1..T12 (T0 folded into bias)
#define K0 (NCH * IN0)         // 27040
#define K1 (NCH * HID)         // 26624
#define RMS_EPS 1e-6f

typedef __bf16 bf16;
typedef __bf16 bf16x4 __attribute__((ext_vector_type(4)));
typedef __bf16 bf16x8 __attribute__((ext_vector_type(8)));
typedef float f32x4 __attribute__((ext_vector_type(4)));

// ---------------------------------------------------------------- utilities
__device__ __forceinline__ void gload16(const void* g, void* l) {
    __builtin_amdgcn_global_load_lds(
        (const __attribute__((address_space(1))) void*)g,
        (__attribute__((address_space(3))) void*)l, 16, 0, 0);
}

__device__ __forceinline__ float rb(float x) { return (float)(bf16)x; }  // round-to-bf16 (RNE)

// bf16-pair packing: both inputs must be exact bf16 values (low 16 bits of f32 zero)
__device__ __forceinline__ unsigned pk2(float lo, float hi) {
    return (__builtin_bit_cast(unsigned, hi) & 0xFFFF0000u) |
           (__builtin_bit_cast(unsigned, lo) >> 16);
}
__device__ __forceinline__ float up_lo(unsigned u) { return __builtin_bit_cast(float, u << 16); }
__device__ __forceinline__ float up_hi(unsigned u) { return __builtin_bit_cast(float, u & 0xFFFF0000u); }

// ---------------------------------------------------- weight convert (f32->bf16, transpose to [N][K])
__global__ __launch_bounds__(256) void convert_w(const float* __restrict__ base,
                                                 const float* __restrict__ poly,
                                                 bf16* __restrict__ dst, int IN, int OUT) {
    __shared__ float tile[32][33];
    int c = blockIdx.z;
    const float* src = (c == 0) ? base : (poly + (size_t)c * IN * OUT);
    int i0 = blockIdx.x * 32, n0 = blockIdx.y * 32;
    int tx = threadIdx.x, ty = threadIdx.y;  // (32,8)
#pragma unroll
    for (int r = 0; r < 4; r++)
        tile[ty + r * 8][tx] = src[(size_t)(i0 + ty + r * 8) * OUT + n0 + tx];
    __syncthreads();
    size_t ldd = (size_t)NCH * IN;
#pragma unroll
    for (int r = 0; r < 4; r++) {
        int n = n0 + ty + r * 8;
        int i = i0 + tx;
        dst[(size_t)n * ldd + (size_t)c * IN + i] = (bf16)tile[tx][ty + r * 8];
    }
}

// bias[n] = f32-sum_i bf16(poly0[i][n])  — parallel: block (64,4), grid OUT/64
__global__ void col_sum_par(const float* __restrict__ w, float* __restrict__ bias,
                            int IN, int OUT) {
    __shared__ float sm[4][64];
    int tx = threadIdx.x, ty = threadIdx.y;
    int n = blockIdx.x * 64 + tx;
    float s = 0.f;
    for (int i = ty; i < IN; i += 4) s += (float)(bf16)w[(size_t)i * OUT + n];
    sm[ty][tx] = s;
    __syncthreads();
    if (ty == 0) bias[n] = sm[0][tx] + sm[1][tx] + sm[2][tx] + sm[3][tx];
}

// ------------------------------------------------------------ feature build (x4 vectorized)
// silu with PER-OP bf16 rounding (matches jax.nn.silu on bf16): e=bf16(exp(-x)); d=bf16(1+e);
// s=bf16(1/d); silu=bf16(x*s).  tanh/Chebyshev recursion in f32 (matches reference).
__device__ __forceinline__ void write_features4(bf16* __restrict__ row, int i,
                                                float4 o, int stride) {
    float x[4] = {o.x, o.y, o.z, o.w};
    bf16x4 t;
#pragma unroll
    for (int l = 0; l < 4; l++) {
        float xb = rb(x[l]);
        float e  = rb(expf(-xb));
        float d  = rb(1.f + e);
        float sg = rb(1.f / d);
        t[l] = (bf16)(xb * sg);
    }
    *(bf16x4*)&row[i] = t;
    float xs[4], Tp[4], Tc[4];
#pragma unroll
    for (int l = 0; l < 4; l++) {
        xs[l] = tanhf(x[l]);
        Tp[l] = 1.f; Tc[l] = xs[l];
        t[l] = (bf16)xs[l];
    }
    *(bf16x4*)&row[(size_t)stride + i] = t;
#pragma unroll
    for (int k = 2; k < NCH; k++) {
#pragma unroll
        for (int l = 0; l < 4; l++) {
            float Tn = 2.f * xs[l] * Tc[l] - Tp[l];
            t[l] = (bf16)Tn;
            Tp[l] = Tc[l]; Tc[l] = Tn;
        }
        *(bf16x4*)&row[(size_t)k * stride + i] = t;
    }
}

__global__ __launch_bounds__(256) void build_f0_v4(const float* __restrict__ h_x,
                                                   const int* __restrict__ tp,
                                                   const float* __restrict__ z,
                                                   const float* __restrict__ pe,
                                                   bf16* __restrict__ F, int m0, int rows) {
    int id = blockIdx.x * 256 + threadIdx.x;
    if (id >= rows * (IN0 / 4)) return;
    int ml = id / (IN0 / 4);
    int i = (id - ml * (IN0 / 4)) * 4;
    int mg = m0 + ml;
    int b = mg >> 11;        // / NT
    float4 v;
    if (i < DM) v = *(const float4*)&h_x[((size_t)b * 128 + 127) * DM + i];
    else if (i < 2 * DM) v = *(const float4*)&pe[(size_t)tp[mg] * DM + (i - DM)];
    else v = *(const float4*)&z[(size_t)mg * ZD + (i - 2 * DM)];
    write_features4(F + (size_t)ml * K0, i, v, IN0);
}

// ---------------------------------------------- fused RMSNorm + layer-1 feature build
// reads H0 (rows x HID f32, gemm0 output), writes F (rows x K1 bf16). H0 not written back.
__global__ __launch_bounds__(256) void rmsnorm_feat(const float* __restrict__ H,
                                                    const float* __restrict__ scale,
                                                    bf16* __restrict__ F) {
    constexpr int VPT = HID / (4 * 256);  // 2
    int row = blockIdx.x;
    const float4* p = (const float4*)(H + (size_t)row * HID);
    const float4* sc = (const float4*)scale;
    float4 v[VPT];
    float s = 0.f;
#pragma unroll
    for (int j = 0; j < VPT; j++) {
        v[j] = p[threadIdx.x + j * 256];
        s += v[j].x * v[j].x + v[j].y * v[j].y + v[j].z * v[j].z + v[j].w * v[j].w;
    }
#pragma unroll
    for (int o = 32; o > 0; o >>= 1) s += __shfl_down(s, o, 64);
    __shared__ float wsum[4];
    if ((threadIdx.x & 63) == 0) wsum[threadIdx.x >> 6] = s;
    __syncthreads();
    s = wsum[0] + wsum[1] + wsum[2] + wsum[3];
    float rs = rsqrtf(s * (1.0f / HID) + RMS_EPS);
    bf16* Frow = F + (size_t)row * K1;
#pragma unroll
    for (int j = 0; j < VPT; j++) {
        float4 sv = sc[threadIdx.x + j * 256];
        float4 o_;
        o_.x = v[j].x * rs * sv.x;
        o_.y = v[j].y * rs * sv.y;
        o_.z = v[j].z * rs * sv.z;
        o_.w = v[j].w * rs * sv.w;
        write_features4(Frow, (threadIdx.x + j * 256) * 4, o_, HID);
    }
}

// ------------------------------------------------------------------ final RMSNorm (in place)
template <int N>
__global__ __launch_bounds__(256) void rmsnorm_k(float* __restrict__ H,
                                                 const float* __restrict__ scale) {
    constexpr int VPT = N / (4 * 256);
    int row = blockIdx.x;
    float4* p = (float4*)(H + (size_t)row * N);
    const float4* sc = (const float4*)scale;
    float4 v[VPT];
    float s = 0.f;
#pragma unroll
    for (int j = 0; j < VPT; j++) {
        v[j] = p[threadIdx.x + j * 256];
        s += v[j].x * v[j].x + v[j].y * v[j].y + v[j].z * v[j].z + v[j].w * v[j].w;
    }
#pragma unroll
    for (int o = 32; o > 0; o >>= 1) s += __shfl_down(s, o, 64);
    __shared__ float wsum[4];
    if ((threadIdx.x & 63) == 0) wsum[threadIdx.x >> 6] = s;
    __syncthreads();
    s = wsum[0] + wsum[1] + wsum[2] + wsum[3];
    float rs = rsqrtf(s * (1.0f / N) + RMS_EPS);
#pragma unroll
    for (int j = 0; j < VPT; j++) {
        float4 sv = sc[threadIdx.x + j * 256];
        float4 o_;
        o_.x = v[j].x * rs * sv.x;
        o_.y = v[j].y * rs * sv.y;
        o_.z = v[j].z * rs * sv.z;
        o_.w = v[j].w * rs * sv.w;
        p[threadIdx.x + j * 256] = o_;
    }
}

// ------------------------------------------------------------------ GEMM, stepwise-bf16 accumulation
// out = bf16(chunk0); out = bf16(out + bf16(bias)); out = bf16(out + bf16(chunk_c)) c=1..12
// Running bf16 sum packed 2-per-register (exact bf16 values; pack is a bit move).
#define BM 128
#define BN 128
#define BK 32
#define GROUP_M 8

__global__ __launch_bounds__(256, 3) void gemm_bias(const bf16* __restrict__ A,
                                                    const bf16* __restrict__ Bt,
                                                    const float* __restrict__ bias,
                                                    float* __restrict__ C,
                                                    int Mrows, int N, int IN) {
    __shared__ __align__(16) bf16 As[BM * BK];   // [m][k]
    __shared__ __align__(16) bf16 Bs[BN * BK];   // [n][k]

    const int K = NCH * IN;
    int nbm = Mrows / BM, nbn = N / BN;
    int pid = blockIdx.x;
    int width = GROUP_M * nbn;
    int group_id = pid / width;
    int first_m = group_id * GROUP_M;
    int gsz = min(nbm - first_m, GROUP_M);
    int mb = first_m + (pid % width) % gsz;
    int nb = (pid % width) / gsz;

    int tid = threadIdx.x;
    int lane = tid & 63, wid = tid >> 6;
    int wm = wid >> 1, wn = wid & 1;  // 2x2 wave grid, each wave 64x64

    const bf16* Ab = A + (size_t)mb * BM * K;
    const bf16* Bb = Bt + (size_t)nb * BN * K;

    const int q0 = tid, q1 = tid + 256;
    const int r0 = q0 >> 2, kk0 = (q0 & 3) * 8;
    const int r1 = q1 >> 2, kk1 = (q1 & 3) * 8;

    const int arow = wm * 64 + (lane & 15);
    const int brow = wn * 64 + (lane & 15);
    const int kqo = (lane >> 4) * 8;

    const int lcol = lane & 15, lrow4 = (lane >> 4) * 4;
    const int crow0 = mb * BM + wm * 64;
    const int ccol0 = nb * BN + wn * 64;

    unsigned outp[4][4][2] = {};   // packed bf16 pairs: [am][bn][epair] = (e0|e1),(e2|e3)

    for (int c = 0; c < NCH; c++) {
        f32x4 acc[4][4] = {};
        const size_t cb = (size_t)c * IN;
        for (int ks = 0; ks < IN; ks += BK) {
            const size_t kb = cb + ks;
            gload16(Ab + (size_t)r0 * K + kb + kk0, (char*)As + q0 * 16);
            gload16(Ab + (size_t)r1 * K + kb + kk1, (char*)As + q1 * 16);
            gload16(Bb + (size_t)r0 * K + kb + kk0, (char*)Bs + q0 * 16);
            gload16(Bb + (size_t)r1 * K + kb + kk1, (char*)Bs + q1 * 16);
            __syncthreads();

            bf16x8 af[4], bfr[4];
#pragma unroll
            for (int am = 0; am < 4; am++)
                af[am] = *(const bf16x8*)&As[(arow + am * 16) * BK + kqo];
#pragma unroll
            for (int bn = 0; bn < 4; bn++)
                bfr[bn] = *(const bf16x8*)&Bs[(brow + bn * 16) * BK + kqo];
#pragma unroll
            for (int am = 0; am < 4; am++)
#pragma unroll
                for (int bn = 0; bn < 4; bn++)
                    acc[am][bn] = __builtin_amdgcn_mfma_f32_16x16x32_bf16(af[am], bfr[bn], acc[am][bn], 0, 0, 0);
            __syncthreads();
        }
        // fold chunk: out = bf16(out + bf16(chunk)); c==0 additionally folds bias next.
        float bv = (c == 0) ? rb(bias[ccol0 + 0 * 16 + lcol]) : 0.f;  // per-bn below
#pragma unroll
        for (int am = 0; am < 4; am++)
#pragma unroll
            for (int bn = 0; bn < 4; bn++)
#pragma unroll
                for (int ep = 0; ep < 2; ep++) {
                    float f0 = up_lo(outp[am][bn][ep]);
                    float f1 = up_hi(outp[am][bn][ep]);
                    f0 = rb(f0 + rb(acc[am][bn][ep * 2 + 0]));
                    f1 = rb(f1 + rb(acc[am][bn][ep * 2 + 1]));
                    outp[am][bn][ep] = pk2(f0, f1);
                }
        if (c == 0) {
#pragma unroll
            for (int bn = 0; bn < 4; bn++) {
                bv = rb(bias[ccol0 + bn * 16 + lcol]);
#pragma unroll
                for (int am = 0; am < 4; am++)
#pragma unroll
                    for (int ep = 0; ep < 2; ep++) {
                        float f0 = rb(up_lo(outp[am][bn][ep]) + bv);
                        float f1 = rb(up_hi(outp[am][bn][ep]) + bv);
                        outp[am][bn][ep] = pk2(f0, f1);
                    }
            }
        }
    }

    // epilogue: C/D layout col=lane&15, row=(lane>>4)*4+reg
#pragma unroll
    for (int bn = 0; bn < 4; bn++) {
        int col = ccol0 + bn * 16 + lcol;
#pragma unroll
        for (int am = 0; am < 4; am++) {
            int row = crow0 + am * 16 + lrow4;
            C[(size_t)(row + 0) * N + col] = up_lo(outp[am][bn][0]);
            C[(size_t)(row + 1) * N + col] = up_hi(outp[am][bn][0]);
            C[(size_t)(row + 2) * N + col] = up_lo(outp[am][bn][1]);
            C[(size_t)(row + 3) * N + col] = up_hi(outp[am][bn][1]);
        }
    }
}

// ------------------------------------------------------------------ host
extern "C" void kernel_launch(void* const* d_in, const int* in_sizes, int n_in,
                              void* d_out, int out_size, void* d_ws, size_t ws_size,
                              hipStream_t stream) {
    const float* h_x   = (const float*)d_in[0];
    const int*   tp    = (const int*)d_in[1];
    const float* z     = (const float*)d_in[2];
    const float* pe    = (const float*)d_in[3];
    const float* base0 = (const float*)d_in[4];
    const float* poly0 = (const float*)d_in[5];
    const float* rms0  = (const float*)d_in[6];
    const float* base1 = (const float*)d_in[7];
    const float* poly1 = (const float*)d_in[8];
    const float* rms1  = (const float*)d_in[9];
    float* out = (float*)d_out;

    char* ws = (char*)d_ws;
    size_t off = 0;
    bf16* wb0 = (bf16*)(ws + off); off += (size_t)HID * K0 * 2;    // 110,755,840
    bf16* wb1 = (bf16*)(ws + off); off += (size_t)OUT1 * K1 * 2;   //  54,525,952
    float* bias0 = (float*)(ws + off); off += HID * 4;
    float* bias1 = (float*)(ws + off); off += OUT1 * 4;
    size_t fixed = off;

    // row-chunk to fit workspace: per row need F (K0 bf16) + H0 (HID f32)
    size_t per_row = (size_t)K0 * 2 + (size_t)HID * 4;
    size_t avail = ws_size > fixed ? ws_size - fixed : 0;
    long long chunk_ll = (long long)(avail / per_row);
    int chunk = (int)(chunk_ll > M_TOT ? M_TOT : chunk_ll);
    chunk &= ~127;                 // multiple of 128
    if (chunk < 128) chunk = 128;  // last resort

    bf16* F = (bf16*)(ws + off); off += (size_t)chunk * K0 * 2;
    float* H0 = (float*)(ws + off);

    dim3 tb(32, 8);
    convert_w<<<dim3(IN0 / 32, HID / 32, NCH), tb, 0, stream>>>(base0, poly0, wb0, IN0, HID);
    convert_w<<<dim3(HID / 32, OUT1 / 32, NCH), tb, 0, stream>>>(base1, poly1, wb1, HID, OUT1);
    col_sum_par<<<HID / 64, dim3(64, 4), 0, stream>>>(poly0, bias0, IN0, HID);
    col_sum_par<<<OUT1 / 64, dim3(64, 4), 0, stream>>>(poly1, bias1, HID, OUT1);

    for (int m0 = 0; m0 < M_TOT; m0 += chunk) {
        int rows = (M_TOT - m0 < chunk) ? (M_TOT - m0) : chunk;
        build_f0_v4<<<(rows * (IN0 / 4) + 255) / 256, 256, 0, stream>>>(h_x, tp, z, pe, F, m0, rows);
        gemm_bias<<<(rows / BM) * (HID / BN), 256, 0, stream>>>(F, wb0, bias0, H0, rows, HID, IN0);
        rmsnorm_feat<<<rows, 256, 0, stream>>>(H0, rms0, F);
        float* o = out + (size_t)m0 * OUT1;
        gemm_bias<<<(rows / BM) * (OUT1 / BN), 256, 0, stream>>>(F, wb1, bias1, o, rows, OUT1, HID);
        rmsnorm_k<OUT1><<<rows, 256, 0, stream>>>(o, rms1);
    }
}

// Round 7
// 3933.162 us; speedup vs baseline: 1.7909x; 1.3068x over previous
//
#include <hip/hip_runtime.h>
#include <hip/hip_bf16.h>
#include <math.h>

#define B_SZ 8
#define NT 2048
#define M_TOT (B_SZ * NT)      // 16384
#define DM 1024                // d_model
#define ZD 32
#define IN0 2080               // 2*DM + ZD
#define HID 2048
#define OUT1 1024
#define NCH 13                 // feature chunks: silu + T1..T12 (T0 folded into bias)
#define PZ 1056                // pos(1024)+z(32) per chunk
#define KPZ (NCH * PZ)         // 13728
#define KCTX (NCH * DM)        // 13312
#define K1 (NCH * HID)         // 26624
#define RMS_EPS 1e-6f

typedef __bf16 bf16;
typedef __bf16 bf16x4 __attribute__((ext_vector_type(4)));
typedef __bf16 bf16x8 __attribute__((ext_vector_type(8)));
typedef float f32x4 __attribute__((ext_vector_type(4)));

// ---------------------------------------------------------------- utilities
__device__ __forceinline__ void gload16(const void* g, void* l) {
    __builtin_amdgcn_global_load_lds(
        (const __attribute__((address_space(1))) void*)g,
        (__attribute__((address_space(3))) void*)l, 16, 0, 0);
}

__device__ __forceinline__ float rb(float x) { return (float)(bf16)x; }  // round-to-bf16 (RNE)

__device__ __forceinline__ unsigned pk2(float lo, float hi) {
    return (__builtin_bit_cast(unsigned, hi) & 0xFFFF0000u) |
           (__builtin_bit_cast(unsigned, lo) >> 16);
}
__device__ __forceinline__ float up_lo(unsigned u) { return __builtin_bit_cast(float, u << 16); }
__device__ __forceinline__ float up_hi(unsigned u) { return __builtin_bit_cast(float, u & 0xFFFF0000u); }

// ------------------------------------- layer-0 weight convert, split ctx / pos+z
// chunk c: c==0 -> base[IN0][HID], else poly0[c][IN0][HID]
// wctx[n][c*1024 + i]        = bf16(src_c[i][n])        for i <  1024
// wposz[n][c*1056 + (i-1024)]= bf16(src_c[i][n])        for i >= 1024
__global__ __launch_bounds__(256) void convert_w0(const float* __restrict__ base,
                                                  const float* __restrict__ poly,
                                                  bf16* __restrict__ wctx,
                                                  bf16* __restrict__ wposz) {
    __shared__ float tile[32][33];
    int c = blockIdx.z;
    const float* src = (c == 0) ? base : (poly + (size_t)c * IN0 * HID);
    int i0 = blockIdx.x * 32, n0 = blockIdx.y * 32;
    int tx = threadIdx.x, ty = threadIdx.y;  // (32,8)
#pragma unroll
    for (int r = 0; r < 4; r++)
        tile[ty + r * 8][tx] = src[(size_t)(i0 + ty + r * 8) * HID + n0 + tx];
    __syncthreads();
#pragma unroll
    for (int r = 0; r < 4; r++) {
        int n = n0 + ty + r * 8;
        int i = i0 + tx;
        bf16 v = (bf16)tile[tx][ty + r * 8];
        if (i < 1024) wctx[(size_t)n * KCTX + (size_t)c * 1024 + i] = v;
        else          wposz[(size_t)n * KPZ + (size_t)c * PZ + (i - 1024)] = v;
    }
}

// generic convert (layer 1): dst[n][c*IN + i] = bf16(src_c[i][n])
__global__ __launch_bounds__(256) void convert_w(const float* __restrict__ base,
                                                 const float* __restrict__ poly,
                                                 bf16* __restrict__ dst, int IN, int OUT) {
    __shared__ float tile[32][33];
    int c = blockIdx.z;
    const float* src = (c == 0) ? base : (poly + (size_t)c * IN * OUT);
    int i0 = blockIdx.x * 32, n0 = blockIdx.y * 32;
    int tx = threadIdx.x, ty = threadIdx.y;
#pragma unroll
    for (int r = 0; r < 4; r++)
        tile[ty + r * 8][tx] = src[(size_t)(i0 + ty + r * 8) * OUT + n0 + tx];
    __syncthreads();
    size_t ldd = (size_t)NCH * IN;
#pragma unroll
    for (int r = 0; r < 4; r++) {
        int n = n0 + ty + r * 8;
        int i = i0 + tx;
        dst[(size_t)n * ldd + (size_t)c * IN + i] = (bf16)tile[tx][ty + r * 8];
    }
}

// ---------------- bias[n] = f32-sum_i bf16(poly[0][i][n]) — two-stage reduce
__global__ void col_sum_s1(const float* __restrict__ w, float* __restrict__ partial,
                           int IN, int OUT) {
    __shared__ float sm[4][64];
    int tx = threadIdx.x, ty = threadIdx.y;  // (64,4)
    int n = blockIdx.x * 64 + tx;
    int s = blockIdx.y;                      // 32 slices
    float acc = 0.f;
    for (int i = 4 * s + ty; i < IN; i += 128) acc += (float)(bf16)w[(size_t)i * OUT + n];
    sm[ty][tx] = acc;
    __syncthreads();
    if (ty == 0) partial[(size_t)s * OUT + n] = sm[0][tx] + sm[1][tx] + sm[2][tx] + sm[3][tx];
}
__global__ void col_sum_s2(const float* __restrict__ partial, float* __restrict__ bias, int OUT) {
    int n = blockIdx.x * 256 + threadIdx.x;
    if (n >= OUT) return;
    float s = 0.f;
#pragma unroll
    for (int k = 0; k < 32; k++) s += partial[(size_t)k * OUT + n];
    bias[n] = s;
}

// ------------------------------------------------------------ feature build
// silu with PER-OP bf16 rounding (matches jax.nn.silu on bf16); tanh/Chebyshev in f32.
__device__ __forceinline__ void write_features4(bf16* __restrict__ row, int i,
                                                float4 o, int stride) {
    float x[4] = {o.x, o.y, o.z, o.w};
    bf16x4 t;
#pragma unroll
    for (int l = 0; l < 4; l++) {
        float xb = rb(x[l]);
        float e  = rb(expf(-xb));
        float d  = rb(1.f + e);
        float sg = rb(1.f / d);
        t[l] = (bf16)(xb * sg);
    }
    *(bf16x4*)&row[i] = t;
    float xs[4], Tp[4], Tc[4];
#pragma unroll
    for (int l = 0; l < 4; l++) {
        xs[l] = tanhf(x[l]);
        Tp[l] = 1.f; Tc[l] = xs[l];
        t[l] = (bf16)xs[l];
    }
    *(bf16x4*)&row[(size_t)stride + i] = t;
#pragma unroll
    for (int k = 2; k < NCH; k++) {
#pragma unroll
        for (int l = 0; l < 4; l++) {
            float Tn = 2.f * xs[l] * Tc[l] - Tp[l];
            t[l] = (bf16)Tn;
            Tp[l] = Tc[l]; Tc[l] = Tn;
        }
        *(bf16x4*)&row[(size_t)k * stride + i] = t;
    }
}

// ctx features: 8 rows x 1024, chunk-stride 1024
__global__ __launch_bounds__(256) void build_fctx(const float* __restrict__ h_x,
                                                  bf16* __restrict__ Fctx) {
    int id = blockIdx.x * 256 + threadIdx.x;  // 8*256
    int b = id >> 8;
    int i = (id & 255) * 4;
    float4 v = *(const float4*)&h_x[((size_t)b * 128 + 127) * DM + i];
    write_features4(Fctx + (size_t)b * KCTX, i, v, DM);
}

// ctx_part[b][c][n] = sum_{i<1024} f32(Fctx[b][c][i]) * f32(wctx[n][c*1024+i])
__global__ void ctx_dot(const bf16* __restrict__ Fctx, const bf16* __restrict__ wctx,
                        float* __restrict__ ctx_part) {
    __shared__ float sm[4][64];
    int tx = threadIdx.x, ty = threadIdx.y;  // (64,4)
    int n = blockIdx.x * 64 + tx;
    int c = blockIdx.y, b = blockIdx.z;
    const bf16* f = Fctx + ((size_t)b * NCH + c) * DM;
    const bf16* wv = wctx + (size_t)n * KCTX + (size_t)c * DM;
    float s = 0.f;
    for (int i = ty; i < DM; i += 4) s += (float)f[i] * (float)wv[i];
    sm[ty][tx] = s;
    __syncthreads();
    if (ty == 0) ctx_part[((size_t)b * NCH + c) * HID + n] = sm[0][tx] + sm[1][tx] + sm[2][tx] + sm[3][tx];
}

// pos+z features per row: 1056 per chunk, 264 quads per row
__global__ __launch_bounds__(256) void build_fposz(const int* __restrict__ tp,
                                                   const float* __restrict__ z,
                                                   const float* __restrict__ pe,
                                                   bf16* __restrict__ F) {
    int id = blockIdx.x * 256 + threadIdx.x;
    if (id >= M_TOT * (PZ / 4)) return;
    int ml = id / (PZ / 4);
    int i = (id - ml * (PZ / 4)) * 4;
    float4 v;
    if (i < DM) v = *(const float4*)&pe[(size_t)tp[ml] * DM + i];
    else v = *(const float4*)&z[(size_t)ml * ZD + (i - DM)];
    write_features4(F + (size_t)ml * KPZ, i, v, PZ);
}

// ---------------------------------------------- fused RMSNorm + layer-1 feature build
__global__ __launch_bounds__(256) void rmsnorm_feat(const float* __restrict__ H,
                                                    const float* __restrict__ scale,
                                                    bf16* __restrict__ F) {
    constexpr int VPT = HID / (4 * 256);  // 2
    int row = blockIdx.x;
    const float4* p = (const float4*)(H + (size_t)row * HID);
    const float4* sc = (const float4*)scale;
    float4 v[VPT];
    float s = 0.f;
#pragma unroll
    for (int j = 0; j < VPT; j++) {
        v[j] = p[threadIdx.x + j * 256];
        s += v[j].x * v[j].x + v[j].y * v[j].y + v[j].z * v[j].z + v[j].w * v[j].w;
    }
#pragma unroll
    for (int o = 32; o > 0; o >>= 1) s += __shfl_down(s, o, 64);
    __shared__ float wsum[4];
    if ((threadIdx.x & 63) == 0) wsum[threadIdx.x >> 6] = s;
    __syncthreads();
    s = wsum[0] + wsum[1] + wsum[2] + wsum[3];
    float rs = rsqrtf(s * (1.0f / HID) + RMS_EPS);
    bf16* Frow = F + (size_t)row * K1;
#pragma unroll
    for (int j = 0; j < VPT; j++) {
        float4 sv = sc[threadIdx.x + j * 256];
        float4 o_;
        o_.x = v[j].x * rs * sv.x;
        o_.y = v[j].y * rs * sv.y;
        o_.z = v[j].z * rs * sv.z;
        o_.w = v[j].w * rs * sv.w;
        write_features4(Frow, (threadIdx.x + j * 256) * 4, o_, HID);
    }
}

// ------------------------------------------------------------------ final RMSNorm (in place)
template <int N>
__global__ __launch_bounds__(256) void rmsnorm_k(float* __restrict__ H,
                                                 const float* __restrict__ scale) {
    constexpr int VPT = N / (4 * 256);
    int row = blockIdx.x;
    float4* p = (float4*)(H + (size_t)row * N);
    const float4* sc = (const float4*)scale;
    float4 v[VPT];
    float s = 0.f;
#pragma unroll
    for (int j = 0; j < VPT; j++) {
        v[j] = p[threadIdx.x + j * 256];
        s += v[j].x * v[j].x + v[j].y * v[j].y + v[j].z * v[j].z + v[j].w * v[j].w;
    }
#pragma unroll
    for (int o = 32; o > 0; o >>= 1) s += __shfl_down(s, o, 64);
    __shared__ float wsum[4];
    if ((threadIdx.x & 63) == 0) wsum[threadIdx.x >> 6] = s;
    __syncthreads();
    s = wsum[0] + wsum[1] + wsum[2] + wsum[3];
    float rs = rsqrtf(s * (1.0f / N) + RMS_EPS);
#pragma unroll
    for (int j = 0; j < VPT; j++) {
        float4 sv = sc[threadIdx.x + j * 256];
        float4 o_;
        o_.x = v[j].x * rs * sv.x;
        o_.y = v[j].y * rs * sv.y;
        o_.z = v[j].z * rs * sv.z;
        o_.w = v[j].w * rs * sv.w;
        p[threadIdx.x + j * 256] = o_;
    }
}

// ------------------------------------------------------------------ GEMM, stepwise-bf16 accumulation
// Per chunk c: acc = [ctx_part (if any)] + MFMA over this chunk's K; then
// out = bf16(out + bf16(acc)); c==0 additionally folds bias (T0 term) next.
#define BM 128
#define BN 128
#define BK 32
#define GROUP_M 8

__global__ __launch_bounds__(256, 4) void gemm_bias(const bf16* __restrict__ A,
                                                    const bf16* __restrict__ Bt,
                                                    const float* __restrict__ bias,
                                                    const float* __restrict__ ctxp,
                                                    float* __restrict__ C,
                                                    int Mrows, int N, int IN) {
    __shared__ __align__(16) bf16 As[BM * BK];   // [m][k]
    __shared__ __align__(16) bf16 Bs[BN * BK];   // [n][k]

    const int K = NCH * IN;
    int nbm = Mrows / BM, nbn = N / BN;
    int pid = blockIdx.x;
    int width = GROUP_M * nbn;
    int group_id = pid / width;
    int first_m = group_id * GROUP_M;
    int gsz = min(nbm - first_m, GROUP_M);
    int mb = first_m + (pid % width) % gsz;
    int nb = (pid % width) / gsz;

    int tid = threadIdx.x;
    int lane = tid & 63, wid = tid >> 6;
    int wm = wid >> 1, wn = wid & 1;  // 2x2 wave grid, each wave 64x64

    const bf16* Ab = A + (size_t)mb * BM * K;
    const bf16* Bb = Bt + (size_t)nb * BN * K;

    const int q0 = tid, q1 = tid + 256;
    const int r0 = q0 >> 2, kk0 = (q0 & 3) * 8;
    const int r1 = q1 >> 2, kk1 = (q1 & 3) * 8;

    const int arow = wm * 64 + (lane & 15);
    const int brow = wn * 64 + (lane & 15);
    const int kqo = (lane >> 4) * 8;

    const int lcol = lane & 15, lrow4 = (lane >> 4) * 4;
    const int crow0 = mb * BM + wm * 64;
    const int ccol0 = nb * BN + wn * 64;
    const int b = (mb * BM) >> 11;   // batch index (layer 0)

    unsigned outp[4][4][2] = {};   // packed bf16 pairs

    for (int c = 0; c < NCH; c++) {
        f32x4 acc[4][4];
        if (ctxp) {
            const float* cp = ctxp + ((size_t)b * NCH + c) * N;
#pragma unroll
            for (int bn = 0; bn < 4; bn++) {
                float cv = cp[ccol0 + bn * 16 + lcol];
#pragma unroll
                for (int am = 0; am < 4; am++) acc[am][bn] = (f32x4){cv, cv, cv, cv};
            }
        } else {
#pragma unroll
            for (int am = 0; am < 4; am++)
#pragma unroll
                for (int bn = 0; bn < 4; bn++) acc[am][bn] = (f32x4){0.f, 0.f, 0.f, 0.f};
        }
        const size_t cb = (size_t)c * IN;
        for (int ks = 0; ks < IN; ks += BK) {
            const size_t kb = cb + ks;
            gload16(Ab + (size_t)r0 * K + kb + kk0, (char*)As + q0 * 16);
            gload16(Ab + (size_t)r1 * K + kb + kk1, (char*)As + q1 * 16);
            gload16(Bb + (size_t)r0 * K + kb + kk0, (char*)Bs + q0 * 16);
            gload16(Bb + (size_t)r1 * K + kb + kk1, (char*)Bs + q1 * 16);
            __syncthreads();

            bf16x8 af[4], bfr[4];
#pragma unroll
            for (int am = 0; am < 4; am++)
                af[am] = *(const bf16x8*)&As[(arow + am * 16) * BK + kqo];
#pragma unroll
            for (int bn = 0; bn < 4; bn++)
                bfr[bn] = *(const bf16x8*)&Bs[(brow + bn * 16) * BK + kqo];
#pragma unroll
            for (int am = 0; am < 4; am++)
#pragma unroll
                for (int bn = 0; bn < 4; bn++)
                    acc[am][bn] = __builtin_amdgcn_mfma_f32_16x16x32_bf16(af[am], bfr[bn], acc[am][bn], 0, 0, 0);
            __syncthreads();
        }
        // fold chunk: out = bf16(out + bf16(chunk))
#pragma unroll
        for (int am = 0; am < 4; am++)
#pragma unroll
            for (int bn = 0; bn < 4; bn++)
#pragma unroll
                for (int ep = 0; ep < 2; ep++) {
                    float f0 = up_lo(outp[am][bn][ep]);
                    float f1 = up_hi(outp[am][bn][ep]);
                    f0 = rb(f0 + rb(acc[am][bn][ep * 2 + 0]));
                    f1 = rb(f1 + rb(acc[am][bn][ep * 2 + 1]));
                    outp[am][bn][ep] = pk2(f0, f1);
                }
        if (c == 0) {
#pragma unroll
            for (int bn = 0; bn < 4; bn++) {
                float bv = rb(bias[ccol0 + bn * 16 + lcol]);
#pragma unroll
                for (int am = 0; am < 4; am++)
#pragma unroll
                    for (int ep = 0; ep < 2; ep++) {
                        float f0 = rb(up_lo(outp[am][bn][ep]) + bv);
                        float f1 = rb(up_hi(outp[am][bn][ep]) + bv);
                        outp[am][bn][ep] = pk2(f0, f1);
                    }
            }
        }
    }

    // epilogue
#pragma unroll
    for (int bn = 0; bn < 4; bn++) {
        int col = ccol0 + bn * 16 + lcol;
#pragma unroll
        for (int am = 0; am < 4; am++) {
            int row = crow0 + am * 16 + lrow4;
            C[(size_t)(row + 0) * N + col] = up_lo(outp[am][bn][0]);
            C[(size_t)(row + 1) * N + col] = up_hi(outp[am][bn][0]);
            C[(size_t)(row + 2) * N + col] = up_lo(outp[am][bn][1]);
            C[(size_t)(row + 3) * N + col] = up_hi(outp[am][bn][1]);
        }
    }
}

// ------------------------------------------------------------------ host
extern "C" void kernel_launch(void* const* d_in, const int* in_sizes, int n_in,
                              void* d_out, int out_size, void* d_ws, size_t ws_size,
                              hipStream_t stream) {
    const float* h_x   = (const float*)d_in[0];
    const int*   tp    = (const int*)d_in[1];
    const float* z     = (const float*)d_in[2];
    const float* pe    = (const float*)d_in[3];
    const float* base0 = (const float*)d_in[4];
    const float* poly0 = (const float*)d_in[5];
    const float* rms0  = (const float*)d_in[6];
    const float* base1 = (const float*)d_in[7];
    const float* poly1 = (const float*)d_in[8];
    const float* rms1  = (const float*)d_in[9];
    float* out = (float*)d_out;

    char* ws = (char*)d_ws;
    size_t off = 0;
    bf16* wctx  = (bf16*)(ws + off); off += (size_t)HID * KCTX * 2;   // 54.5 MB
    bf16* wposz = (bf16*)(ws + off); off += (size_t)HID * KPZ * 2;    // 56.2 MB
    bf16* wb1   = (bf16*)(ws + off); off += (size_t)OUT1 * K1 * 2;    // 54.5 MB
    float* bias0 = (float*)(ws + off); off += HID * 4;
    float* bias1 = (float*)(ws + off); off += OUT1 * 4;
    float* partial = (float*)(ws + off); off += 32 * HID * 4;         // 256 KB (reused)
    bf16* Fctx = (bf16*)(ws + off); off += (size_t)B_SZ * KCTX * 2;   // 208 KB
    float* ctx_part = (float*)(ws + off); off += (size_t)B_SZ * NCH * HID * 4;  // 852 KB
    float* H0 = (float*)(ws + off); off += (size_t)M_TOT * HID * 4;   // 134 MB
    size_t fixed = off;

    // big region: Fposz (layer 0), then overlaid by F1 (layer 1)
    bf16* FBIG = (bf16*)(ws + off);
    size_t avail = ws_size > fixed ? ws_size - fixed : 0;
    // layer-1 chunk rows that fit in FBIG
    long long chunk_ll = (long long)(avail / ((size_t)K1 * 2));
    int chunk = (int)(chunk_ll > M_TOT ? M_TOT : chunk_ll);
    chunk &= ~127;
    if (chunk < 128) chunk = 128;

    dim3 tb(32, 8);
    // weights
    convert_w0<<<dim3(IN0 / 32, HID / 32, NCH), tb, 0, stream>>>(base0, poly0, wctx, wposz);
    convert_w<<<dim3(HID / 32, OUT1 / 32, NCH), tb, 0, stream>>>(base1, poly1, wb1, HID, OUT1);
    // biases (T0 chunks)
    col_sum_s1<<<dim3(HID / 64, 32), dim3(64, 4), 0, stream>>>(poly0, partial, IN0, HID);
    col_sum_s2<<<HID / 256, 256, 0, stream>>>(partial, bias0, HID);
    col_sum_s1<<<dim3(OUT1 / 64, 32), dim3(64, 4), 0, stream>>>(poly1, partial, HID, OUT1);
    col_sum_s2<<<OUT1 / 256, 256, 0, stream>>>(partial, bias1, OUT1);
    // ctx table
    build_fctx<<<8, 256, 0, stream>>>(h_x, Fctx);
    ctx_dot<<<dim3(HID / 64, NCH, B_SZ), dim3(64, 4), 0, stream>>>(Fctx, wctx, ctx_part);
    // layer 0
    bf16* Fposz = FBIG;
    build_fposz<<<(M_TOT * (PZ / 4) + 255) / 256, 256, 0, stream>>>(tp, z, pe, Fposz);
    gemm_bias<<<(M_TOT / BM) * (HID / BN), 256, 0, stream>>>(Fposz, wposz, bias0, ctx_part,
                                                             H0, M_TOT, HID, PZ);
    // layer 1 (chunked over rows; F1 overlays Fposz)
    bf16* F1 = FBIG;
    for (int m0 = 0; m0 < M_TOT; m0 += chunk) {
        int rows = (M_TOT - m0 < chunk) ? (M_TOT - m0) : chunk;
        rmsnorm_feat<<<rows, 256, 0, stream>>>(H0 + (size_t)m0 * HID, rms0, F1);
        float* o = out + (size_t)m0 * OUT1;
        gemm_bias<<<(rows / BM) * (OUT1 / BN), 256, 0, stream>>>(F1, wb1, bias1, nullptr,
                                                                 o, rows, OUT1, HID);
        rmsnorm_k<OUT1><<<rows, 256, 0, stream>>>(o, rms1);
    }
}